// Round 14
// baseline (32.667 us; speedup 1.0000x reference)
//
#include <hip/hip_runtime.h>

// CTC batch cost, forward-backward split, f64 probability domain with
// wave-uniform power-of-2 renorm every 32 steps (exact; integer c).
// Round-14 change vs round-11 (bit-identical math): 4 batch items per block
// (512 threads = 8 waves) so each SIMD holds 2 co-resident waves -> dependent
// f64/DPP latencies overlap across waves. Grid 128 blocks.
// Per item: wave 0 = forward alpha_255 (t=0..255), wave 1 = backward beta_255
// (t=511..256); loglik = log2(sum_s alpha*beta) + ca + cb.
// Lane l holds extended states {2l, 2l+1}; S=97 -> lanes 0..48 live.

constexpr int Bc = 512, Tc = 512, Cc = 128, Lc = 48;
constexpr int IPB = 4;                   // items per block
constexpr double DEPS = 1e-7;
constexpr float FNEG = -1e30f;
constexpr float LN2F = 0.69314718055994530942f;

#define DPP_WAVE_SHR1 0x138
#define DPP_WAVE_SHL1 0x130

__device__ __forceinline__ double dpp64_shr1(double x) {
    // lane l <- lane l-1; lane 0 <- 0.0
    long long u = __double_as_longlong(x);
    int a = __builtin_amdgcn_update_dpp(0, (int)u,         DPP_WAVE_SHR1, 0xF, 0xF, false);
    int b = __builtin_amdgcn_update_dpp(0, (int)(u >> 32), DPP_WAVE_SHR1, 0xF, 0xF, false);
    return __longlong_as_double(((long long)b << 32) | (unsigned int)a);
}
__device__ __forceinline__ double dpp64_shl1(double x) {
    // lane l <- lane l+1; lane 63 <- 0.0
    long long u = __double_as_longlong(x);
    int a = __builtin_amdgcn_update_dpp(0, (int)u,         DPP_WAVE_SHL1, 0xF, 0xF, false);
    int b = __builtin_amdgcn_update_dpp(0, (int)(u >> 32), DPP_WAVE_SHL1, 0xF, 0xF, false);
    return __longlong_as_double(((long long)b << 32) | (unsigned int)a);
}

__device__ __forceinline__ float lae2(float a, float b) {  // final reduce only
    float m = fmaxf(a, b);
    float d = fabsf(a - b);
    return m + __log2f(1.0f + __builtin_amdgcn_exp2f(-d));
}
__device__ __forceinline__ float blankpf(float praw) {
    return __uint_as_float((unsigned)
        __builtin_amdgcn_readlane(__float_as_uint(praw), 63));
}
__device__ __forceinline__ float log2d(double x) {
    // log2 of a positive normal f64; zero/denormal -> log-zero
    if (!(x > 0.0)) return FNEG;
    long long u = __double_as_longlong(x);
    int e = (int)((u >> 52) & 0x7FF);
    if (e == 0) return FNEG;
    double m = __longlong_as_double((u & 0x000FFFFFFFFFFFFFLL) | 0x3FF0000000000000LL);
    return __log2f((float)m) + (float)(e - 1023);
}

__global__ __launch_bounds__(IPB * 128, 2)
void ctc_fb_kernel(const int* __restrict__ y_true,
                   const float* __restrict__ y_pred,
                   float* __restrict__ out) {
    const int lane = threadIdx.x & 63;
    const int wave = (threadIdx.x >> 6) & 1;   // direction
    const int sub  = threadIdx.x >> 7;         // item within block
    const int b = blockIdx.x * IPB + sub;

    const float* yb = y_pred + (size_t)b * Tc * Cc;

    const int lab = (lane < Lc) ? y_true[b * Lc + lane] : (Cc - 1);
    const int labm1 = __builtin_amdgcn_ds_bpermute(((lane + 63) & 63) << 2, lab);
    const int labp1 = __builtin_amdgcn_ds_bpermute(((lane + 1) & 63) << 2, lab);
    const bool skip  = (lab != (Cc - 1)) && (lab != labm1);   // into 2l+1 from 2l-1
    const bool skipN = (labp1 != (Cc - 1)) && (labp1 != lab); // out of 2l+1 into 2l+3
    const bool validhi = (lane < Lc);
    const bool lane0 = (lane == 0);

    __shared__ double sblo[IPB][64], sbhi[IPB][64];
    __shared__ int sbc[IPB][64];

    double lo = 0.0, hi = 0.0;
    int c = 0;   // wave-uniform log2 scale (exact integer)

    auto renorm = [&]() {   // once per 32 steps; wave max via shuffles
        double mx = fmax(lo, hi);
        #pragma unroll
        for (int mk = 1; mk < 64; mk <<= 1)
            mx = fmax(mx, __shfl_xor(mx, mk, 64));
        int e = (int)((__double_as_longlong(mx) >> 52) & 0x7FF) - 1023;
        double sc = __longlong_as_double((long long)(1023 - e) << 52);  // exact 2^-e
        lo *= sc; hi *= sc;
        c += e;
    };

    if (wave == 0) {
        // -------- forward: alpha_255, consume p_0..p_255 --------
        auto dostep = [&](float praw) {
            double pb = (double)blankpf(praw) + DEPS;
            double ph = validhi ? ((double)praw + DEPS) : 0.0;
            double sh = dpp64_shr1(hi);        // alpha[2l-1]
            double a3 = skip ? sh : 0.0;
            double nlo = (lo + sh) * pb;       // even state (blank)
            double nhi = (hi + lo + a3) * ph;  // odd state (label)
            lo = nlo; hi = nhi;
        };
        float pf[32];
        #pragma unroll
        for (int j = 0; j < 32; ++j) pf[j] = yb[j * Cc + lab];
        {   // group 0 with t=0 init
            float praw = pf[0];
            pf[0] = yb[32 * Cc + lab];
            lo = lane0 ? ((double)blankpf(praw) + DEPS) : 0.0;  // state 0 = blank
            hi = lane0 ? ((double)praw + DEPS) : 0.0;           // state 1 = label[0]
            #pragma unroll
            for (int j = 1; j < 32; ++j) {
                float r = pf[j];
                pf[j] = yb[(32 + j) * Cc + lab];
                dostep(r);
            }
            renorm();
        }
        #pragma unroll 1
        for (int g = 1; g < 7; ++g) {
            const float* ybg = yb + (size_t)(g * 32 + 32) * Cc;
            #pragma unroll
            for (int j = 0; j < 32; ++j) {
                float r = pf[j];
                pf[j] = ybg[j * Cc + lab];
                dostep(r);
            }
            renorm();
        }
        #pragma unroll
        for (int j = 0; j < 32; ++j) dostep(pf[j]);
        renorm();
    } else {
        // -------- backward: beta_255, consume p_511..p_256 --------
        // q[s] = beta_{t+1}[s] * p_{t+1}[s]
        // beta_t[2l]   = q[2l] + q[2l+1]
        // beta_t[2l+1] = q[2l+1] + q[2l+2] + (skipN ? q[2l+3] : 0)
        auto dostep = [&](float praw) {
            double pb = (double)blankpf(praw) + DEPS;
            double ph = validhi ? ((double)praw + DEPS) : 0.0;
            double qlo = lo * pb;              // q[2l]
            double qhi = hi * ph;              // q[2l+1]
            double qlo_n = dpp64_shl1(qlo);    // q[2l+2]
            double qhi_n = dpp64_shl1(qhi);    // q[2l+3]
            double nb = skipN ? (qlo_n + qhi_n) : qlo_n;
            lo = qlo + qhi;
            hi = qhi + nb;
        };
        // init beta_511: state 96 (lane48.lo) = 1, state 95 (lane47.hi) = 1
        lo = (lane == 48) ? 1.0 : 0.0;
        hi = (lane == 47) ? 1.0 : 0.0;
        float pf[32];
        #pragma unroll
        for (int j = 0; j < 32; ++j) pf[j] = yb[(size_t)(511 - j) * Cc + lab];
        #pragma unroll 1
        for (int g = 0; g < 7; ++g) {
            #pragma unroll
            for (int j = 0; j < 32; ++j) {
                float r = pf[j];
                pf[j] = yb[(size_t)(511 - (g * 32 + 32 + j)) * Cc + lab];
                dostep(r);
            }
            renorm();
        }
        #pragma unroll
        for (int j = 0; j < 32; ++j) dostep(pf[j]);
        renorm();
        sblo[sub][lane] = lo;
        sbhi[sub][lane] = hi;
        sbc[sub][lane]  = c;
    }

    __syncthreads();

    if (wave == 0) {
        // loglik = log2( sum_s alpha_255[s]*beta_255[s] ) + ca + cb
        double plo = lo * sblo[sub][lane];
        double phi = hi * sbhi[sub][lane];
        float ctot = (float)(c + sbc[sub][lane]);
        float yl = log2d(plo) + ctot;
        float yh = log2d(phi) + ctot;
        float v = lae2(yl, yh);
        #pragma unroll
        for (int mk = 1; mk < 64; mk <<= 1)
            v = lae2(v, __shfl_xor(v, mk, 64));
        if (lane0) out[b] = -(v * LN2F);
    }
}

extern "C" void kernel_launch(void* const* d_in, const int* in_sizes, int n_in,
                              void* d_out, int out_size, void* d_ws, size_t ws_size,
                              hipStream_t stream) {
    const int* y_true = (const int*)d_in[0];
    const float* y_pred = (const float*)d_in[1];
    float* out = (float*)d_out;
    hipLaunchKernelGGL(ctc_fb_kernel, dim3(Bc / IPB), dim3(IPB * 128), 0, stream,
                       y_true, y_pred, out);
}